// Round 2
// baseline (469.797 us; speedup 1.0000x reference)
//
#include <hip/hip_runtime.h>

// PointPillarScatter: out[b, c, y, x] = pillar_features[p, c] where
// coords[p] = (b, z=0, y, x); zeros elsewhere. Output [8, 64, 496, 432] fp32.
//
// Gather formulation: build spatial->pillar index map in d_ws (6.9 MB),
// then one pass writes every output element once (coalesced float4 NT stores).

#define PX_NX 432
#define PX_NY 496
#define PX_C 64
#define PX_NYX (PX_NY * PX_NX) // 214272, divisible by 4

// native clang vector type — __builtin_nontemporal_store rejects the
// HIP_vector_type struct float4, but accepts ext_vector_type
typedef float floatx4 __attribute__((ext_vector_type(4)));

// ---- kernel 1: init index map to -1 -------------------------------------
__global__ void pps_init_map(int4* __restrict__ map4, int n4) {
    int i = blockIdx.x * blockDim.x + threadIdx.x;
    if (i < n4) {
        map4[i] = make_int4(-1, -1, -1, -1);
    }
}

// ---- kernel 2: scatter pillar ids into the map --------------------------
// coords: [P,4] int32 (batch, z, y, x); unique per batch by construction.
__global__ void pps_scatter_ids(const int4* __restrict__ coords,
                                int* __restrict__ map, int P) {
    int p = blockIdx.x * blockDim.x + threadIdx.x;
    if (p < P) {
        int4 cv = coords[p]; // x=batch, y=z, z=y, w=x
        int g = cv.x * PX_NYX + cv.y + cv.z * PX_NX + cv.w;
        map[g] = p;
    }
}

// ---- kernel 3: gather + write full output -------------------------------
// One thread = 4 consecutive x positions for one (b, y); loops over all 64
// channels. Writes are coalesced float4 (consecutive lanes -> consecutive x),
// nontemporal (pure streaming, no reuse). Feature loads are unconditional
// from a clamped pillar id (safe address) + select, so no exec-mask churn;
// invalid lanes re-read pillar 0's L1-resident lines.
__global__ void pps_gather(const float* __restrict__ feat,
                           const int* __restrict__ map,
                           float* __restrict__ out, int total4) {
    int i = blockIdx.x * blockDim.x + threadIdx.x;
    if (i >= total4) return;

    const int xq = PX_NX / 4; // 108
    int x4 = i % xq;
    int t = i / xq;
    int y = t % PX_NY;
    int b = t / PX_NY;

    int sbase = b * PX_NYX + y * PX_NX + x4 * 4; // divisible by 4
    int4 pid = ((const int4*)map)[sbase >> 2];

    bool v0 = pid.x >= 0, v1 = pid.y >= 0, v2 = pid.z >= 0, v3 = pid.w >= 0;
    const float* f0 = feat + (size_t)(v0 ? pid.x : 0) * PX_C;
    const float* f1 = feat + (size_t)(v1 ? pid.y : 0) * PX_C;
    const float* f2 = feat + (size_t)(v2 ? pid.z : 0) * PX_C;
    const float* f3 = feat + (size_t)(v3 ? pid.w : 0) * PX_C;

    float* ob = out + (size_t)b * ((size_t)PX_C * PX_NYX)
                    + (size_t)y * PX_NX + (size_t)x4 * 4;

#pragma unroll 8
    for (int c = 0; c < PX_C; ++c) {
        float a0 = f0[c];
        float a1 = f1[c];
        float a2 = f2[c];
        float a3 = f3[c];
        floatx4 v;
        v.x = v0 ? a0 : 0.0f;
        v.y = v1 ? a1 : 0.0f;
        v.z = v2 ? a2 : 0.0f;
        v.w = v3 ? a3 : 0.0f;
        __builtin_nontemporal_store(v, (floatx4*)(ob + (size_t)c * PX_NYX));
    }
}

extern "C" void kernel_launch(void* const* d_in, const int* in_sizes, int n_in,
                              void* d_out, int out_size, void* d_ws, size_t ws_size,
                              hipStream_t stream) {
    const float* feat = (const float*)d_in[0];
    const int* coords = (const int*)d_in[1];
    // d_in[2] = batch_size scalar (unused; derived from out_size)
    float* out = (float*)d_out;
    int* map = (int*)d_ws; // B*NY*NX int32 = 6.86 MB scratch

    int B = out_size / (PX_C * PX_NYX); // 8
    int P = in_sizes[1] / 4;            // 128000

    int map_n = B * PX_NYX;     // 1,714,176
    int map_n4 = map_n / 4;     // 428,544
    int total4 = B * PX_NY * (PX_NX / 4); // 428,544

    pps_init_map<<<(map_n4 + 255) / 256, 256, 0, stream>>>((int4*)map, map_n4);
    pps_scatter_ids<<<(P + 255) / 256, 256, 0, stream>>>((const int4*)coords, map, P);
    pps_gather<<<(total4 + 255) / 256, 256, 0, stream>>>(feat, map, out, total4);
}

// Round 3
// 461.281 us; speedup vs baseline: 1.0185x; 1.0185x over previous
//
#include <hip/hip_runtime.h>

// PointPillarScatter: out[b, c, y, x] = pillar_features[p, c] where
// coords[p] = (b, z=0, y, x); zeros elsewhere. Output [8, 64, 496, 432] fp32.
//
// Gather formulation: build spatial->pillar index map in d_ws (6.9 MB),
// then one pass writes every output element once (coalesced float4 NT stores).
// R3: float4 feat loads + 4x4 register transpose, zero-row instead of
// per-element cndmask, CSPLIT=4 for more latency-hiding waves.

#define PX_NX 432
#define PX_NY 496
#define PX_C 64
#define PX_NYX (PX_NY * PX_NX) // 214272, divisible by 4
#define CSPLIT 4               // channel groups per (b,y,x4) position

typedef float floatx4 __attribute__((ext_vector_type(4)));

// ---- kernel 1: init index map to -1, zero-row to 0 ----------------------
__global__ void pps_init_map(int4* __restrict__ map4, int n4) {
    int i = blockIdx.x * blockDim.x + threadIdx.x;
    if (i < n4) {
        map4[i] = make_int4(-1, -1, -1, -1);
    }
    // 64-float zero row lives right after the map (n4*4 ints in)
    if (blockIdx.x == 0 && threadIdx.x < 16) {
        map4[n4 + threadIdx.x] = make_int4(0, 0, 0, 0);
    }
}

// ---- kernel 2: scatter pillar ids into the map --------------------------
// coords: [P,4] int32 (batch, z, y, x); unique per batch by construction.
__global__ void pps_scatter_ids(const int4* __restrict__ coords,
                                int* __restrict__ map, int P) {
    int p = blockIdx.x * blockDim.x + threadIdx.x;
    if (p < P) {
        int4 cv = coords[p]; // x=batch, y=z, z=y, w=x
        int g = cv.x * PX_NYX + cv.y + cv.z * PX_NX + cv.w;
        map[g] = p;
    }
}

// ---- kernel 3: gather + write full output -------------------------------
// One thread = 4 consecutive x positions for one (b, y), 16 channels
// (CSPLIT=4). Feat is read as float4 (16B gathers) and transposed 4x4 in
// registers; stores are coalesced float4 NT (consecutive lanes ->
// consecutive x). Empty positions read from a zeroed row (no selects).
__global__ void pps_gather(const float* __restrict__ feat,
                           const int* __restrict__ map,
                           const float* __restrict__ zrow,
                           float* __restrict__ out, int total) {
    int i = blockIdx.x * blockDim.x + threadIdx.x;
    if (i >= total) return;

    const int xq = PX_NX / 4; // 108
    int x4 = i % xq;
    int t = i / xq;
    int y = t % PX_NY;
    int t2 = t / PX_NY;
    int b = t2 % 8;       // B==8 fixed by problem (out_size check in launch)
    int cs = t2 / 8;      // channel group 0..CSPLIT-1

    int sbase = b * PX_NYX + y * PX_NX + x4 * 4; // divisible by 4
    int4 pid = ((const int4*)map)[sbase >> 2];

    const float* r0 = (pid.x >= 0) ? feat + (size_t)pid.x * PX_C : zrow;
    const float* r1 = (pid.y >= 0) ? feat + (size_t)pid.y * PX_C : zrow;
    const float* r2 = (pid.z >= 0) ? feat + (size_t)pid.z * PX_C : zrow;
    const float* r3 = (pid.w >= 0) ? feat + (size_t)pid.w * PX_C : zrow;

    const int c_lo = cs * (PX_C / CSPLIT); // 16 channels per thread
    float* ob = out + (size_t)b * ((size_t)PX_C * PX_NYX)
                    + (size_t)y * PX_NX + (size_t)x4 * 4;

#pragma unroll
    for (int cc = 0; cc < (PX_C / CSPLIT) / 4; ++cc) { // 4 chunks of 4 c's
        int c0 = c_lo + cc * 4;
        floatx4 q0 = *(const floatx4*)(r0 + c0);
        floatx4 q1 = *(const floatx4*)(r1 + c0);
        floatx4 q2 = *(const floatx4*)(r2 + c0);
        floatx4 q3 = *(const floatx4*)(r3 + c0);
#pragma unroll
        for (int k = 0; k < 4; ++k) {
            floatx4 v;
            v.x = q0[k];
            v.y = q1[k];
            v.z = q2[k];
            v.w = q3[k];
            __builtin_nontemporal_store(
                v, (floatx4*)(ob + (size_t)(c0 + k) * PX_NYX));
        }
    }
}

extern "C" void kernel_launch(void* const* d_in, const int* in_sizes, int n_in,
                              void* d_out, int out_size, void* d_ws, size_t ws_size,
                              hipStream_t stream) {
    const float* feat = (const float*)d_in[0];
    const int* coords = (const int*)d_in[1];
    float* out = (float*)d_out;
    int* map = (int*)d_ws; // B*NY*NX int32 = 6.86 MB + 256 B zero row

    int B = out_size / (PX_C * PX_NYX); // 8
    int P = in_sizes[1] / 4;            // 128000

    int map_n = B * PX_NYX;     // 1,714,176
    int map_n4 = map_n / 4;     // 428,544
    const float* zrow = (const float*)(map + map_n); // 64 zeroed floats

    int total = B * PX_NY * (PX_NX / 4) * CSPLIT; // 1,714,176 threads

    pps_init_map<<<(map_n4 + 255) / 256, 256, 0, stream>>>((int4*)map, map_n4);
    pps_scatter_ids<<<(P + 255) / 256, 256, 0, stream>>>((const int4*)coords, map, P);
    pps_gather<<<(total + 255) / 256, 256, 0, stream>>>(feat, map, zrow, out, total);
}